// Round 1
// baseline (4358.479 us; speedup 1.0000x reference)
//
#include <hip/hip_runtime.h>
#include <math.h>

#define FDIM   128
#define TWOF   256
#define NRBF_  20
#define INDIM  276          // 2F + NRBF
#define XSTRIDE 280         // INDIM padded to multiple of 4 (16B-aligned float4 rows)
#define TE     32           // edges per workgroup

// Decide whether edge_index arrived as int64 (odd dwords == high words == 0)
// or int32 (odd dwords are real indices, ~never all zero). flag=1 -> int32.
__global__ void sniff_idx(const int* __restrict__ ei, int nsample, int* __restrict__ flag) {
    __shared__ int any;
    if (threadIdx.x == 0) any = 0;
    __syncthreads();
    int nz = 0;
    for (int i = threadIdx.x; i < nsample; i += blockDim.x)
        nz |= (ei[2 * i + 1] != 0);
    if (nz) atomicOr(&any, 1);
    __syncthreads();
    if (threadIdx.x == 0) *flag = any;
}

// out[0:NF] = s ; out[NF:4NF] = v   (vectorized float4 copy)
__global__ void init_out(const float4* __restrict__ s4, const float4* __restrict__ v4,
                         float4* __restrict__ out4, int nf4, int total4) {
    for (int i = blockIdx.x * blockDim.x + threadIdx.x; i < total4;
         i += gridDim.x * blockDim.x)
        out4[i] = (i < nf4) ? s4[i] : v4[i - nf4];
}

__launch_bounds__(256)
__global__ void edge_kernel(const float* __restrict__ s,
                            const float* __restrict__ pos,
                            const int* __restrict__ ei,
                            const float* __restrict__ W1, const float* __restrict__ b1,
                            const float* __restrict__ W2, const float* __restrict__ b2,
                            const float* __restrict__ Wsm, const float* __restrict__ bsm,
                            const float* __restrict__ Wvm, const float* __restrict__ bvm,
                            const float* __restrict__ centers, const float* __restrict__ widths,
                            const int* __restrict__ flag,
                            float* __restrict__ out, int N, int E) {
    __shared__ __align__(16) float Xs[TE][XSTRIDE];   // [edge][feature 0..275]
    __shared__ __align__(16) float Hs[TE][TWOF];      // h1, then reused for h2
    __shared__ int   ssrc[TE], sdst[TE], svalid[TE];
    __shared__ float sdir[3][TE];

    const int t  = threadIdx.x;
    const int e0 = blockIdx.x * TE;
    const int i64 = (*flag == 0);

    // ---- Phase A: per-edge prep (32 threads, one edge each)
    if (t < TE) {
        int e = e0 + t;
        int valid = (e < E);
        int srcn = 0, dstn = 0;
        if (valid) {
            if (i64) { srcn = ei[2 * e];     dstn = ei[2 * (E + e)]; }
            else     { srcn = ei[e];         dstn = ei[E + e]; }
        }
        ssrc[t] = srcn; sdst[t] = dstn; svalid[t] = valid;
        float rx = pos[dstn * 3 + 0] - pos[srcn * 3 + 0];
        float ry = pos[dstn * 3 + 1] - pos[srcn * 3 + 1];
        float rz = pos[dstn * 3 + 2] - pos[srcn * 3 + 2];
        float dist = sqrtf(rx * rx + ry * ry + rz * rz);
        float inv = dist > 0.f ? 1.f / dist : 0.f;
        sdir[0][t] = rx * inv; sdir[1][t] = ry * inv; sdir[2][t] = rz * inv;
#pragma unroll
        for (int k = 0; k < NRBF_; ++k) {
            float u = (dist - centers[k]) / (widths[k] + 1e-8f);
            Xs[t][TWOF + k] = __expf(-u * u);
        }
    }
    __syncthreads();

    // ---- Phase B: gather s[src] (cols 0..127), s[dst] (cols 128..255)
    {
        const int half = t >> 7;        // waves 0,1 -> src ; waves 2,3 -> dst
        const int f = t & (FDIM - 1);
#pragma unroll 4
        for (int e = 0; e < TE; ++e) {
            int node = half ? sdst[e] : ssrc[e];
            Xs[e][half * FDIM + f] = s[node * FDIM + f];
        }
    }
    __syncthreads();

    float acc[TE];

    // ---- Layer 1: h1 = silu(X @ W1 + b1)   K=276, N=256 (thread t owns col t)
#pragma unroll
    for (int e = 0; e < TE; ++e) acc[e] = 0.f;
    for (int k = 0; k < INDIM; k += 4) {
        float w0 = W1[(k + 0) * TWOF + t];
        float w1 = W1[(k + 1) * TWOF + t];
        float w2 = W1[(k + 2) * TWOF + t];
        float w3 = W1[(k + 3) * TWOF + t];
#pragma unroll
        for (int e = 0; e < TE; ++e) {
            float4 x = *(const float4*)&Xs[e][k];
            acc[e] = fmaf(x.x, w0, acc[e]);
            acc[e] = fmaf(x.y, w1, acc[e]);
            acc[e] = fmaf(x.z, w2, acc[e]);
            acc[e] = fmaf(x.w, w3, acc[e]);
        }
    }
    {
        float bb = b1[t];
#pragma unroll
        for (int e = 0; e < TE; ++e) {
            float h = acc[e] + bb;
            Hs[e][t] = h * __builtin_amdgcn_rcpf(1.f + __expf(-h));
        }
    }
    __syncthreads();

    // ---- Layer 2: h2 = silu(h1 @ W2 + b2)   K=256, N=256
#pragma unroll
    for (int e = 0; e < TE; ++e) acc[e] = 0.f;
    for (int k = 0; k < TWOF; k += 4) {
        float w0 = W2[(k + 0) * TWOF + t];
        float w1 = W2[(k + 1) * TWOF + t];
        float w2 = W2[(k + 2) * TWOF + t];
        float w3 = W2[(k + 3) * TWOF + t];
#pragma unroll
        for (int e = 0; e < TE; ++e) {
            float4 x = *(const float4*)&Hs[e][k];
            acc[e] = fmaf(x.x, w0, acc[e]);
            acc[e] = fmaf(x.y, w1, acc[e]);
            acc[e] = fmaf(x.z, w2, acc[e]);
            acc[e] = fmaf(x.w, w3, acc[e]);
        }
    }
    {
        float bb = b2[t];
        __syncthreads();                 // all reads of h1 done before overwrite
#pragma unroll
        for (int e = 0; e < TE; ++e) {
            float h = acc[e] + bb;
            Hs[e][t] = h * __builtin_amdgcn_rcpf(1.f + __expf(-h));
        }
    }
    __syncthreads();

    // ---- Output heads: t<128 -> ds feature t ; t>=128 -> dv_mag feature t-128
    const float* W3 = (t < FDIM) ? Wsm : Wvm;   // wave-uniform (waves 0,1 vs 2,3)
    const float* b3 = (t < FDIM) ? bsm : bvm;
    const int f = t & (FDIM - 1);
#pragma unroll
    for (int e = 0; e < TE; ++e) acc[e] = 0.f;
    for (int k = 0; k < TWOF; k += 4) {
        float w0 = W3[(k + 0) * FDIM + f];
        float w1 = W3[(k + 1) * FDIM + f];
        float w2 = W3[(k + 2) * FDIM + f];
        float w3 = W3[(k + 3) * FDIM + f];
#pragma unroll
        for (int e = 0; e < TE; ++e) {
            float4 x = *(const float4*)&Hs[e][k];
            acc[e] = fmaf(x.x, w0, acc[e]);
            acc[e] = fmaf(x.y, w1, acc[e]);
            acc[e] = fmaf(x.z, w2, acc[e]);
            acc[e] = fmaf(x.w, w3, acc[e]);
        }
    }
    float bfin = b3[f];

    float* outs = out;                  // [N][F]
    float* outv = out + N * FDIM;       // [N][3][F]
    if (t < FDIM) {
        for (int e = 0; e < TE; ++e) {
            if (!svalid[e]) continue;
            atomicAdd(&outs[sdst[e] * FDIM + f], acc[e] + bfin);
        }
    } else {
        for (int e = 0; e < TE; ++e) {
            if (!svalid[e]) continue;
            float m = acc[e] + bfin;
            int base = sdst[e] * 3 * FDIM + f;
            atomicAdd(&outv[base],            sdir[0][e] * m);
            atomicAdd(&outv[base + FDIM],     sdir[1][e] * m);
            atomicAdd(&outv[base + 2 * FDIM], sdir[2][e] * m);
        }
    }
}

extern "C" void kernel_launch(void* const* d_in, const int* in_sizes, int n_in,
                              void* d_out, int out_size, void* d_ws, size_t ws_size,
                              hipStream_t stream) {
    const float* s   = (const float*)d_in[0];
    const float* v   = (const float*)d_in[1];
    const float* pos = (const float*)d_in[2];
    const int*   ei  = (const int*)d_in[3];
    const float* W1  = (const float*)d_in[4];
    const float* b1  = (const float*)d_in[5];
    const float* W2  = (const float*)d_in[6];
    const float* b2  = (const float*)d_in[7];
    const float* Wsm = (const float*)d_in[8];
    const float* bsm = (const float*)d_in[9];
    const float* Wvm = (const float*)d_in[10];
    const float* bvm = (const float*)d_in[11];
    const float* centers = (const float*)d_in[12];
    const float* widths  = (const float*)d_in[13];
    float* out = (float*)d_out;

    int N = in_sizes[0] / FDIM;
    int E = in_sizes[3] / 2;
    int* flag = (int*)d_ws;

    int nsample = E < 1024 ? E : 1024;
    hipLaunchKernelGGL(sniff_idx, dim3(1), dim3(256), 0, stream, ei, nsample, flag);

    int nf4    = (N * FDIM) / 4;   // float4 count of s
    int total4 = N * FDIM;         // (N*F + 3*N*F)/4
    hipLaunchKernelGGL(init_out, dim3(8192), dim3(256), 0, stream,
                       (const float4*)s, (const float4*)v, (float4*)out, nf4, total4);

    int nblocks = (E + TE - 1) / TE;
    hipLaunchKernelGGL(edge_kernel, dim3(nblocks), dim3(256), 0, stream,
                       s, pos, ei, W1, b1, W2, b2, Wsm, bsm, Wvm, bvm,
                       centers, widths, flag, out, N, E);
}

// Round 2
// 1123.647 us; speedup vs baseline: 3.8789x; 3.8789x over previous
//
#include <hip/hip_runtime.h>
#include <math.h>

#define FDIM   128
#define TWOF   256
#define NRBF_  20
#define INDIM  276
#define K1PAD  288          // INDIM padded to multiple of 32
#define XS     296          // X row stride in bf16: 37 * 8 elems -> odd # of 16B chunks
#define HS     264          // H row stride in bf16: 33 * 8 elems -> odd # of 16B chunks
#define TE     64           // edges per workgroup

typedef __bf16 bf16x8 __attribute__((ext_vector_type(8)));
typedef __bf16 bf16x4 __attribute__((ext_vector_type(4)));
typedef float  f32x4  __attribute__((ext_vector_type(4)));

// ---------------- helper kernels ----------------

__global__ void sniff_idx(const int* __restrict__ ei, int nsample, int* __restrict__ flag) {
    __shared__ int any;
    if (threadIdx.x == 0) any = 0;
    __syncthreads();
    int nz = 0;
    for (int i = threadIdx.x; i < nsample; i += blockDim.x)
        nz |= (ei[2 * i + 1] != 0);
    if (nz) atomicOr(&any, 1);
    __syncthreads();
    if (threadIdx.x == 0) *flag = any;
}

__global__ void init_out(const float4* __restrict__ s4, const float4* __restrict__ v4,
                         float4* __restrict__ out4, int nf4, int total4) {
    for (int i = blockIdx.x * blockDim.x + threadIdx.x; i < total4;
         i += gridDim.x * blockDim.x)
        out4[i] = (i < nf4) ? s4[i] : v4[i - nf4];
}

// Transpose + bf16-convert weights into d_ws:
//   W1t [256][288]  (zero-padded K)
//   W2t [256][256]
//   W3t [256][256]  rows 0..127 = Ws cols, rows 128..255 = Wv cols
__global__ void prep_weights(const float* __restrict__ W1, const float* __restrict__ W2,
                             const float* __restrict__ Ws, const float* __restrict__ Wv,
                             __bf16* __restrict__ W1t, __bf16* __restrict__ W2t,
                             __bf16* __restrict__ W3t) {
    int id = blockIdx.x * 256 + threadIdx.x;
    const int n1 = 256 * K1PAD;            // 73728
    if (id < n1) {
        int n = id / K1PAD, k = id - n * K1PAD;
        W1t[id] = (k < INDIM) ? (__bf16)W1[k * TWOF + n] : (__bf16)0.f;
    } else if (id < n1 + 65536) {
        int j = id - n1; int n = j >> 8, k = j & 255;
        W2t[j] = (__bf16)W2[k * TWOF + n];
    } else if (id < n1 + 131072) {
        int j = id - n1 - 65536; int n = j >> 8, k = j & 255;
        W3t[j] = (n < FDIM) ? (__bf16)Ws[k * FDIM + n]
                            : (__bf16)Wv[k * FDIM + (n - FDIM)];
    }
}

// ---------------- main edge kernel ----------------

__launch_bounds__(256, 2)
__global__ void edge_kernel(const float* __restrict__ s,
                            const float* __restrict__ pos,
                            const int* __restrict__ ei,
                            const float* __restrict__ b1, const float* __restrict__ b2,
                            const float* __restrict__ bsm, const float* __restrict__ bvm,
                            const float* __restrict__ centers, const float* __restrict__ widths,
                            const __bf16* __restrict__ W1t, const __bf16* __restrict__ W2t,
                            const __bf16* __restrict__ W3t,
                            const int* __restrict__ flag,
                            float* __restrict__ out, int N, int E) {
    __shared__ __align__(16) __bf16 Xs[TE][XS];
    __shared__ __align__(16) __bf16 Hs[TE][HS];
    __shared__ float sdir[3][TE];
    __shared__ int ssrc[TE], sdst[TE], svalid[TE];

    const int t    = threadIdx.x;
    const int lane = t & 63;
    const int wave = t >> 6;
    const int e0   = blockIdx.x * TE;
    const int i64  = (*flag == 0);

    // ---- Phase A: per-edge prep (64 threads, one edge each)
    if (t < TE) {
        int e = e0 + t;
        int valid = (e < E);
        int srcn = 0, dstn = 0;
        if (valid) {
            if (i64) { srcn = ei[2 * e]; dstn = ei[2 * (E + e)]; }
            else     { srcn = ei[e];     dstn = ei[E + e]; }
        }
        ssrc[t] = srcn; sdst[t] = dstn; svalid[t] = valid;
        float rx = pos[dstn * 3 + 0] - pos[srcn * 3 + 0];
        float ry = pos[dstn * 3 + 1] - pos[srcn * 3 + 1];
        float rz = pos[dstn * 3 + 2] - pos[srcn * 3 + 2];
        float dist = sqrtf(rx * rx + ry * ry + rz * rz);
        float inv = dist > 0.f ? 1.f / dist : 0.f;
        sdir[0][t] = rx * inv; sdir[1][t] = ry * inv; sdir[2][t] = rz * inv;
#pragma unroll
        for (int k = 0; k < 32; ++k) {
            float val = 0.f;
            if (k < NRBF_) {
                float u = (dist - centers[k]) / (widths[k] + 1e-8f);
                val = __expf(-u * u);
            }
            Xs[t][TWOF + k] = (__bf16)val;
        }
    }
    __syncthreads();

    // ---- Phase B: gather s[src]/s[dst] -> Xs (bf16). Wave w handles edges 16w..16w+15.
    {
        const int c    = lane;          // 0..63: feature chunk (4 floats each)
        const int half = c >> 5;        // 0 = src, 1 = dst
        const int q    = c & 31;        // float4 index within the 128 floats
        const float4* s4 = (const float4*)s;
#pragma unroll 4
        for (int i = 0; i < 16; ++i) {
            int e = wave * 16 + i;
            int node = half ? sdst[e] : ssrc[e];
            float4 x = s4[node * 32 + q];
            bf16x4 b; b.x = (__bf16)x.x; b.y = (__bf16)x.y; b.z = (__bf16)x.z; b.w = (__bf16)x.w;
            *(bf16x4*)&Xs[e][half * FDIM + q * 4] = b;
        }
    }
    __syncthreads();

    const int l15 = lane & 15;
    const int kg  = (lane >> 4) * 8;
    const int nbase = wave * 64;

    f32x4 acc[4][4];

    // ================= Layer 1: h1 = silu(X @ W1 + b1), K=288 =================
#pragma unroll
    for (int et = 0; et < 4; ++et)
#pragma unroll
        for (int nt = 0; nt < 4; ++nt) acc[et][nt] = (f32x4)0.f;

    for (int kc = 0; kc < K1PAD; kc += 32) {
        bf16x8 a[4], b[4];
#pragma unroll
        for (int et = 0; et < 4; ++et)
            a[et] = *(const bf16x8*)&Xs[et * 16 + l15][kc + kg];
#pragma unroll
        for (int nt = 0; nt < 4; ++nt)
            b[nt] = *(const bf16x8*)&W1t[(nbase + nt * 16 + l15) * K1PAD + kc + kg];
#pragma unroll
        for (int nt = 0; nt < 4; ++nt)
#pragma unroll
            for (int et = 0; et < 4; ++et)
                acc[et][nt] = __builtin_amdgcn_mfma_f32_16x16x32_bf16(a[et], b[nt], acc[et][nt], 0, 0, 0);
    }
    {
#pragma unroll
        for (int nt = 0; nt < 4; ++nt) {
            int n = nbase + nt * 16 + l15;
            float bb = b1[n];
#pragma unroll
            for (int et = 0; et < 4; ++et)
#pragma unroll
                for (int r = 0; r < 4; ++r) {
                    int m = et * 16 + (lane >> 4) * 4 + r;
                    float h = acc[et][nt][r] + bb;
                    Hs[m][n] = (__bf16)(h * __builtin_amdgcn_rcpf(1.f + __expf(-h)));
                }
        }
    }
    __syncthreads();

    // ================= Layer 2: h2 = silu(h1 @ W2 + b2), K=256 =================
#pragma unroll
    for (int et = 0; et < 4; ++et)
#pragma unroll
        for (int nt = 0; nt < 4; ++nt) acc[et][nt] = (f32x4)0.f;

    for (int kc = 0; kc < TWOF; kc += 32) {
        bf16x8 a[4], b[4];
#pragma unroll
        for (int et = 0; et < 4; ++et)
            a[et] = *(const bf16x8*)&Hs[et * 16 + l15][kc + kg];
#pragma unroll
        for (int nt = 0; nt < 4; ++nt)
            b[nt] = *(const bf16x8*)&W2t[(nbase + nt * 16 + l15) * TWOF + kc + kg];
#pragma unroll
        for (int nt = 0; nt < 4; ++nt)
#pragma unroll
            for (int et = 0; et < 4; ++et)
                acc[et][nt] = __builtin_amdgcn_mfma_f32_16x16x32_bf16(a[et], b[nt], acc[et][nt], 0, 0, 0);
    }
    __syncthreads();   // all reads of h1 complete before overwrite
    {
#pragma unroll
        for (int nt = 0; nt < 4; ++nt) {
            int n = nbase + nt * 16 + l15;
            float bb = b2[n];
#pragma unroll
            for (int et = 0; et < 4; ++et)
#pragma unroll
                for (int r = 0; r < 4; ++r) {
                    int m = et * 16 + (lane >> 4) * 4 + r;
                    float h = acc[et][nt][r] + bb;
                    Hs[m][n] = (__bf16)(h * __builtin_amdgcn_rcpf(1.f + __expf(-h)));
                }
        }
    }
    __syncthreads();

    // ========== Layer 3: [ds | dv_mag] = h2 @ [Ws | Wv] + [bs | bv], K=256 ==========
    // Wave w owns ds features [32w..32w+32) (nt 0,1) and dv features [32w..32w+32) (nt 2,3).
#pragma unroll
    for (int et = 0; et < 4; ++et)
#pragma unroll
        for (int nt = 0; nt < 4; ++nt) acc[et][nt] = (f32x4)0.f;

    for (int kc = 0; kc < TWOF; kc += 32) {
        bf16x8 a[4], b[4];
#pragma unroll
        for (int et = 0; et < 4; ++et)
            a[et] = *(const bf16x8*)&Hs[et * 16 + l15][kc + kg];
#pragma unroll
        for (int nt = 0; nt < 4; ++nt) {
            int rowbase = ((nt >= 2) ? FDIM : 0) + wave * 32 + (nt & 1) * 16 + l15;
            b[nt] = *(const bf16x8*)&W3t[rowbase * TWOF + kc + kg];
        }
#pragma unroll
        for (int nt = 0; nt < 4; ++nt)
#pragma unroll
            for (int et = 0; et < 4; ++et)
                acc[et][nt] = __builtin_amdgcn_mfma_f32_16x16x32_bf16(a[et], b[nt], acc[et][nt], 0, 0, 0);
    }

    float b3v[4];
#pragma unroll
    for (int nt = 0; nt < 4; ++nt) {
        int n = wave * 32 + (nt & 1) * 16 + l15;
        b3v[nt] = (nt < 2) ? bsm[n] : bvm[n];
    }

    float* outs = out;                  // [N][F]
    float* outv = out + (long)N * FDIM; // [N][3][F]
#pragma unroll
    for (int et = 0; et < 4; ++et) {
#pragma unroll
        for (int r = 0; r < 4; ++r) {
            int m = et * 16 + (lane >> 4) * 4 + r;
            if (!svalid[m]) continue;
            int dst = sdst[m];
            float dx = sdir[0][m], dy = sdir[1][m], dz = sdir[2][m];
#pragma unroll
            for (int nt = 0; nt < 4; ++nt) {
                int n = wave * 32 + (nt & 1) * 16 + l15;
                float val = acc[et][nt][r] + b3v[nt];
                if (nt < 2) {
                    atomicAdd(&outs[dst * FDIM + n], val);
                } else {
                    int base = dst * 3 * FDIM + n;
                    atomicAdd(&outv[base],            dx * val);
                    atomicAdd(&outv[base + FDIM],     dy * val);
                    atomicAdd(&outv[base + 2 * FDIM], dz * val);
                }
            }
        }
    }
}

extern "C" void kernel_launch(void* const* d_in, const int* in_sizes, int n_in,
                              void* d_out, int out_size, void* d_ws, size_t ws_size,
                              hipStream_t stream) {
    const float* s   = (const float*)d_in[0];
    const float* v   = (const float*)d_in[1];
    const float* pos = (const float*)d_in[2];
    const int*   ei  = (const int*)d_in[3];
    const float* W1  = (const float*)d_in[4];
    const float* b1  = (const float*)d_in[5];
    const float* W2  = (const float*)d_in[6];
    const float* b2  = (const float*)d_in[7];
    const float* Wsm = (const float*)d_in[8];
    const float* bsm = (const float*)d_in[9];
    const float* Wvm = (const float*)d_in[10];
    const float* bvm = (const float*)d_in[11];
    const float* centers = (const float*)d_in[12];
    const float* widths  = (const float*)d_in[13];
    float* out = (float*)d_out;

    int N = in_sizes[0] / FDIM;
    int E = in_sizes[3] / 2;

    // workspace layout
    int*    flag = (int*)d_ws;
    __bf16* W1t  = (__bf16*)((char*)d_ws + 256);
    __bf16* W2t  = W1t + 256 * K1PAD;
    __bf16* W3t  = W2t + 256 * TWOF;

    int nsample = E < 1024 ? E : 1024;
    hipLaunchKernelGGL(sniff_idx, dim3(1), dim3(256), 0, stream, ei, nsample, flag);

    int nprep = 256 * K1PAD + 2 * 256 * TWOF;       // 204800
    hipLaunchKernelGGL(prep_weights, dim3((nprep + 255) / 256), dim3(256), 0, stream,
                       W1, W2, Wsm, Wvm, W1t, W2t, W3t);

    int nf4    = (N * FDIM) / 4;
    int total4 = N * FDIM;
    hipLaunchKernelGGL(init_out, dim3(8192), dim3(256), 0, stream,
                       (const float4*)s, (const float4*)v, (float4*)out, nf4, total4);

    int nblocks = (E + TE - 1) / TE;
    hipLaunchKernelGGL(edge_kernel, dim3(nblocks), dim3(256), 0, stream,
                       s, pos, ei, b1, b2, bsm, bvm, centers, widths,
                       W1t, W2t, W3t, flag, out, N, E);
}

// Round 3
// 806.614 us; speedup vs baseline: 5.4034x; 1.3930x over previous
//
#include <hip/hip_runtime.h>
#include <math.h>

#define FDIM   128
#define TWOF   256
#define NRBF_  20
#define INDIM  276
#define K1PAD  288          // INDIM padded to multiple of 32
#define XS     296          // X row stride in bf16 (odd # of 16B chunks)
#define HS     264          // H row stride in bf16 (odd # of 16B chunks)
#define EOS    264          // EO staging stride in bf16
#define TE     64           // edges per workgroup

typedef __bf16 bf16x8 __attribute__((ext_vector_type(8)));
typedef __bf16 bf16x4 __attribute__((ext_vector_type(4)));
typedef float  f32x4  __attribute__((ext_vector_type(4)));

__device__ inline float blo(unsigned p){ return __uint_as_float(p << 16); }
__device__ inline float bhi(unsigned p){ return __uint_as_float(p & 0xffff0000u); }

// ---------------- helper kernels ----------------

__global__ void sniff_idx(const int* __restrict__ ei, int nsample, int* __restrict__ flag) {
    __shared__ int any;
    if (threadIdx.x == 0) any = 0;
    __syncthreads();
    int nz = 0;
    for (int i = threadIdx.x; i < nsample; i += blockDim.x)
        nz |= (ei[2 * i + 1] != 0);
    if (nz) atomicOr(&any, 1);
    __syncthreads();
    if (threadIdx.x == 0) *flag = any;
}

__global__ void init_out(const float4* __restrict__ s4, const float4* __restrict__ v4,
                         float4* __restrict__ out4, int nf4, int total4) {
    for (int i = blockIdx.x * blockDim.x + threadIdx.x; i < total4;
         i += gridDim.x * blockDim.x)
        out4[i] = (i < nf4) ? s4[i] : v4[i - nf4];
}

__global__ void prep_weights(const float* __restrict__ W1, const float* __restrict__ W2,
                             const float* __restrict__ Ws, const float* __restrict__ Wv,
                             __bf16* __restrict__ W1t, __bf16* __restrict__ W2t,
                             __bf16* __restrict__ W3t) {
    int id = blockIdx.x * 256 + threadIdx.x;
    const int n1 = 256 * K1PAD;
    if (id < n1) {
        int n = id / K1PAD, k = id - n * K1PAD;
        W1t[id] = (k < INDIM) ? (__bf16)W1[k * TWOF + n] : (__bf16)0.f;
    } else if (id < n1 + 65536) {
        int j = id - n1; int n = j >> 8, k = j & 255;
        W2t[j] = (__bf16)W2[k * TWOF + n];
    } else if (id < n1 + 131072) {
        int j = id - n1 - 65536; int n = j >> 8, k = j & 255;
        W3t[j] = (n < FDIM) ? (__bf16)Ws[k * FDIM + n]
                            : (__bf16)Wv[k * FDIM + (n - FDIM)];
    }
}

// ---------------- CSR build ----------------

__global__ void zero_hist(int* __restrict__ hist, int N) {
    int i = blockIdx.x * 256 + threadIdx.x;
    if (i < N) hist[i] = 0;
}

__global__ void hist_k(const int* __restrict__ ei, const int* __restrict__ flag,
                       int* __restrict__ hist, int E) {
    int e = blockIdx.x * 256 + threadIdx.x;
    if (e >= E) return;
    int dst = (*flag == 0) ? ei[2 * (E + e)] : ei[E + e];
    atomicAdd(&hist[dst], 1);
}

// block scans 1024 elems (4/thread), writes local-exclusive + block sums
__global__ void scan_a(const int* __restrict__ hist, int* __restrict__ loc,
                       int* __restrict__ bsum, int N) {
    __shared__ int sums[256];
    int t = threadIdx.x;
    int base = blockIdx.x * 1024 + t * 4;
    int v0 = (base + 0 < N) ? hist[base + 0] : 0;
    int v1 = (base + 1 < N) ? hist[base + 1] : 0;
    int v2 = (base + 2 < N) ? hist[base + 2] : 0;
    int v3 = (base + 3 < N) ? hist[base + 3] : 0;
    int s = v0 + v1 + v2 + v3;
    sums[t] = s;
    __syncthreads();
    for (int off = 1; off < 256; off <<= 1) {
        int x = (t >= off) ? sums[t - off] : 0;
        __syncthreads();
        sums[t] += x;
        __syncthreads();
    }
    int excl = sums[t] - s;
    if (t == 255) bsum[blockIdx.x] = sums[255];
    if (base + 0 < N) loc[base + 0] = excl; excl += v0;
    if (base + 1 < N) loc[base + 1] = excl; excl += v1;
    if (base + 2 < N) loc[base + 2] = excl; excl += v2;
    if (base + 3 < N) loc[base + 3] = excl;
}

__global__ void scan_b(int* __restrict__ bsum, int nb) {
    if (threadIdx.x == 0 && blockIdx.x == 0) {
        int run = 0;
        for (int i = 0; i < nb; ++i) { int v = bsum[i]; bsum[i] = run; run += v; }
    }
}

__global__ void scan_c(const int* __restrict__ loc, const int* __restrict__ bsum,
                       int* __restrict__ rs, int* __restrict__ cursor, int N, int E) {
    int i = blockIdx.x * 256 + threadIdx.x;
    if (i < N) {
        int v = loc[i] + bsum[i >> 10];
        rs[i] = v; cursor[i] = v;
    }
    if (i == 0) rs[N] = E;
}

__global__ void scatter_k(const int* __restrict__ ei, const int* __restrict__ flag,
                          int* __restrict__ cursor, int* __restrict__ elist, int E) {
    int e = blockIdx.x * 256 + threadIdx.x;
    if (e >= E) return;
    int dst = (*flag == 0) ? ei[2 * (E + e)] : ei[E + e];
    int pos = atomicAdd(&cursor[dst], 1);
    elist[pos] = e;
}

// ---------------- main edge kernel ----------------
// CSR=1: write per-edge [ds|dvm] bf16 rows to EO (no atomics).
// CSR=0: legacy atomicAdd into out.

template<int CSR>
__launch_bounds__(256, 2)
__global__ void edge_kernel(const float* __restrict__ s,
                            const float* __restrict__ pos,
                            const int* __restrict__ ei,
                            const float* __restrict__ b1, const float* __restrict__ b2,
                            const float* __restrict__ bsm, const float* __restrict__ bvm,
                            const float* __restrict__ centers, const float* __restrict__ widths,
                            const __bf16* __restrict__ W1t, const __bf16* __restrict__ W2t,
                            const __bf16* __restrict__ W3t,
                            const int* __restrict__ flag,
                            __bf16* __restrict__ EO,
                            float* __restrict__ dirx, float* __restrict__ diry,
                            float* __restrict__ dirz,
                            float* __restrict__ out, int N, int E) {
    __shared__ __align__(16) __bf16 Xs[TE][XS];
    __shared__ __align__(16) __bf16 Hs[TE][HS];
    __shared__ float sdir[3][TE];
    __shared__ int ssrc[TE], sdst[TE], svalid[TE];

    const int t    = threadIdx.x;
    const int lane = t & 63;
    const int wave = t >> 6;
    const int e0   = blockIdx.x * TE;
    const int i64  = (*flag == 0);

    // ---- Phase A: per-edge prep
    if (t < TE) {
        int e = e0 + t;
        int valid = (e < E);
        int srcn = 0, dstn = 0;
        if (valid) {
            if (i64) { srcn = ei[2 * e]; dstn = ei[2 * (E + e)]; }
            else     { srcn = ei[e];     dstn = ei[E + e]; }
        }
        ssrc[t] = srcn; sdst[t] = dstn; svalid[t] = valid;
        float rx = pos[dstn * 3 + 0] - pos[srcn * 3 + 0];
        float ry = pos[dstn * 3 + 1] - pos[srcn * 3 + 1];
        float rz = pos[dstn * 3 + 2] - pos[srcn * 3 + 2];
        float dist = sqrtf(rx * rx + ry * ry + rz * rz);
        float inv = dist > 0.f ? 1.f / dist : 0.f;
        float dx = rx * inv, dy = ry * inv, dz = rz * inv;
        sdir[0][t] = dx; sdir[1][t] = dy; sdir[2][t] = dz;
        if (CSR && valid) { dirx[e] = dx; diry[e] = dy; dirz[e] = dz; }
#pragma unroll
        for (int k = 0; k < 32; ++k) {
            float val = 0.f;
            if (k < NRBF_) {
                float u = (dist - centers[k]) / (widths[k] + 1e-8f);
                val = __expf(-u * u);
            }
            Xs[t][TWOF + k] = (__bf16)val;
        }
    }
    __syncthreads();

    // ---- Phase B: gather s[src]/s[dst] -> Xs
    {
        const int half = lane >> 5;
        const int q    = lane & 31;
        const float4* s4 = (const float4*)s;
#pragma unroll 4
        for (int i = 0; i < 16; ++i) {
            int e = wave * 16 + i;
            int node = half ? sdst[e] : ssrc[e];
            float4 x = s4[node * 32 + q];
            bf16x4 b; b.x = (__bf16)x.x; b.y = (__bf16)x.y; b.z = (__bf16)x.z; b.w = (__bf16)x.w;
            *(bf16x4*)&Xs[e][half * FDIM + q * 4] = b;
        }
    }
    __syncthreads();

    const int l15 = lane & 15;
    const int kg  = (lane >> 4) * 8;
    const int nbase = wave * 64;

    f32x4 acc[4][4];

    // ================= Layer 1: K=288 =================
#pragma unroll
    for (int et = 0; et < 4; ++et)
#pragma unroll
        for (int nt = 0; nt < 4; ++nt) acc[et][nt] = (f32x4)0.f;
    {
        const __bf16* bp[4];
#pragma unroll
        for (int nt = 0; nt < 4; ++nt)
            bp[nt] = &W1t[(size_t)(nbase + nt * 16 + l15) * K1PAD + kg];
        bf16x8 bcur[4];
#pragma unroll
        for (int nt = 0; nt < 4; ++nt) bcur[nt] = *(const bf16x8*)bp[nt];
#pragma unroll
        for (int kc = 0; kc < K1PAD; kc += 32) {
            bf16x8 bnxt[4];
            if (kc + 32 < K1PAD) {
#pragma unroll
                for (int nt = 0; nt < 4; ++nt)
                    bnxt[nt] = *(const bf16x8*)(bp[nt] + kc + 32);
            }
            bf16x8 a[4];
#pragma unroll
            for (int et = 0; et < 4; ++et)
                a[et] = *(const bf16x8*)&Xs[et * 16 + l15][kc + kg];
#pragma unroll
            for (int nt = 0; nt < 4; ++nt)
#pragma unroll
                for (int et = 0; et < 4; ++et)
                    acc[et][nt] = __builtin_amdgcn_mfma_f32_16x16x32_bf16(a[et], bcur[nt], acc[et][nt], 0, 0, 0);
#pragma unroll
            for (int nt = 0; nt < 4; ++nt) bcur[nt] = bnxt[nt];
        }
    }
#pragma unroll
    for (int nt = 0; nt < 4; ++nt) {
        int n = nbase + nt * 16 + l15;
        float bb = b1[n];
#pragma unroll
        for (int et = 0; et < 4; ++et)
#pragma unroll
            for (int r = 0; r < 4; ++r) {
                int m = et * 16 + (lane >> 4) * 4 + r;
                float h = acc[et][nt][r] + bb;
                Hs[m][n] = (__bf16)(h * __builtin_amdgcn_rcpf(1.f + __expf(-h)));
            }
    }
    __syncthreads();

    // ================= Layer 2: K=256 =================
#pragma unroll
    for (int et = 0; et < 4; ++et)
#pragma unroll
        for (int nt = 0; nt < 4; ++nt) acc[et][nt] = (f32x4)0.f;
    {
        const __bf16* bp[4];
#pragma unroll
        for (int nt = 0; nt < 4; ++nt)
            bp[nt] = &W2t[(size_t)(nbase + nt * 16 + l15) * TWOF + kg];
        bf16x8 bcur[4];
#pragma unroll
        for (int nt = 0; nt < 4; ++nt) bcur[nt] = *(const bf16x8*)bp[nt];
#pragma unroll
        for (int kc = 0; kc < TWOF; kc += 32) {
            bf16x8 bnxt[4];
            if (kc + 32 < TWOF) {
#pragma unroll
                for (int nt = 0; nt < 4; ++nt)
                    bnxt[nt] = *(const bf16x8*)(bp[nt] + kc + 32);
            }
            bf16x8 a[4];
#pragma unroll
            for (int et = 0; et < 4; ++et)
                a[et] = *(const bf16x8*)&Hs[et * 16 + l15][kc + kg];
#pragma unroll
            for (int nt = 0; nt < 4; ++nt)
#pragma unroll
                for (int et = 0; et < 4; ++et)
                    acc[et][nt] = __builtin_amdgcn_mfma_f32_16x16x32_bf16(a[et], bcur[nt], acc[et][nt], 0, 0, 0);
#pragma unroll
            for (int nt = 0; nt < 4; ++nt) bcur[nt] = bnxt[nt];
        }
    }
    __syncthreads();   // all reads of h1 complete before overwrite
#pragma unroll
    for (int nt = 0; nt < 4; ++nt) {
        int n = nbase + nt * 16 + l15;
        float bb = b2[n];
#pragma unroll
        for (int et = 0; et < 4; ++et)
#pragma unroll
            for (int r = 0; r < 4; ++r) {
                int m = et * 16 + (lane >> 4) * 4 + r;
                float h = acc[et][nt][r] + bb;
                Hs[m][n] = (__bf16)(h * __builtin_amdgcn_rcpf(1.f + __expf(-h)));
            }
    }
    __syncthreads();

    // ================= Layer 3: K=256 =================
#pragma unroll
    for (int et = 0; et < 4; ++et)
#pragma unroll
        for (int nt = 0; nt < 4; ++nt) acc[et][nt] = (f32x4)0.f;
    {
        const __bf16* bp[4];
#pragma unroll
        for (int nt = 0; nt < 4; ++nt) {
            int rowbase = ((nt >= 2) ? FDIM : 0) + wave * 32 + (nt & 1) * 16 + l15;
            bp[nt] = &W3t[(size_t)rowbase * TWOF + kg];
        }
        bf16x8 bcur[4];
#pragma unroll
        for (int nt = 0; nt < 4; ++nt) bcur[nt] = *(const bf16x8*)bp[nt];
#pragma unroll
        for (int kc = 0; kc < TWOF; kc += 32) {
            bf16x8 bnxt[4];
            if (kc + 32 < TWOF) {
#pragma unroll
                for (int nt = 0; nt < 4; ++nt)
                    bnxt[nt] = *(const bf16x8*)(bp[nt] + kc + 32);
            }
            bf16x8 a[4];
#pragma unroll
            for (int et = 0; et < 4; ++et)
                a[et] = *(const bf16x8*)&Hs[et * 16 + l15][kc + kg];
#pragma unroll
            for (int nt = 0; nt < 4; ++nt)
#pragma unroll
                for (int et = 0; et < 4; ++et)
                    acc[et][nt] = __builtin_amdgcn_mfma_f32_16x16x32_bf16(a[et], bcur[nt], acc[et][nt], 0, 0, 0);
#pragma unroll
            for (int nt = 0; nt < 4; ++nt) bcur[nt] = bnxt[nt];
        }
    }

    float b3v[4];
#pragma unroll
    for (int nt = 0; nt < 4; ++nt) {
        int n = wave * 32 + (nt & 1) * 16 + l15;
        b3v[nt] = (nt < 2) ? bsm[n] : bvm[n];
    }

    if (CSR) {
        // stage [ds|dvm] bf16 into LDS (overlay on Xs, dead now), then coalesced copy
        __bf16 (*EOs)[EOS] = (__bf16(*)[EOS])(&Xs[0][0]);
#pragma unroll
        for (int nt = 0; nt < 4; ++nt) {
            int col = ((nt >= 2) ? FDIM : 0) + wave * 32 + (nt & 1) * 16 + l15;
            float bb = b3v[nt];
#pragma unroll
            for (int et = 0; et < 4; ++et)
#pragma unroll
                for (int r = 0; r < 4; ++r) {
                    int m = et * 16 + (lane >> 4) * 4 + r;
                    EOs[m][col] = (__bf16)(acc[et][nt][r] + bb);
                }
        }
        __syncthreads();
        uint4* dst4 = (uint4*)(EO + (size_t)e0 * 256);
#pragma unroll
        for (int j = 0; j < 8; ++j) {
            int flat = j * 256 + t;          // 0..2047
            int row = flat >> 5, col = flat & 31;
            dst4[(size_t)row * 32 + col] = *(const uint4*)&EOs[row][col * 8];
        }
    } else {
        float* outs = out;
        float* outv = out + (size_t)N * FDIM;
#pragma unroll
        for (int et = 0; et < 4; ++et) {
#pragma unroll
            for (int r = 0; r < 4; ++r) {
                int m = et * 16 + (lane >> 4) * 4 + r;
                if (!svalid[m]) continue;
                int dst = sdst[m];
                float dx = sdir[0][m], dy = sdir[1][m], dz = sdir[2][m];
#pragma unroll
                for (int nt = 0; nt < 4; ++nt) {
                    int n = wave * 32 + (nt & 1) * 16 + l15;
                    float val = acc[et][nt][r] + b3v[nt];
                    if (nt < 2) {
                        atomicAdd(&outs[dst * FDIM + n], val);
                    } else {
                        int base = dst * 3 * FDIM + n;
                        atomicAdd(&outv[base],            dx * val);
                        atomicAdd(&outv[base + FDIM],     dy * val);
                        atomicAdd(&outv[base + 2 * FDIM], dz * val);
                    }
                }
            }
        }
    }
}

// ---------------- node aggregation (wave per node) ----------------

__launch_bounds__(256)
__global__ void node_kernel(const float* __restrict__ s, const float* __restrict__ v,
                            const __bf16* __restrict__ EO,
                            const float* __restrict__ dirx, const float* __restrict__ diry,
                            const float* __restrict__ dirz,
                            const int* __restrict__ rs, const int* __restrict__ elist,
                            float* __restrict__ out, int N) {
    int wave = threadIdx.x >> 6, lane = threadIdx.x & 63;
    int n = blockIdx.x * 4 + wave;
    if (n >= N) return;
    int beg = rs[n], end = rs[n + 1];

    float a0 = 0.f, a1 = 0.f;
    float vx0 = 0.f, vx1 = 0.f, vy0 = 0.f, vy1 = 0.f, vz0 = 0.f, vz1 = 0.f;
    const unsigned* EO32 = (const unsigned*)EO;

    for (int i = beg; i < end; ++i) {
        int e = elist[i];
        unsigned pds = EO32[(size_t)e * 128 + lane];
        unsigned pvm = EO32[(size_t)e * 128 + 64 + lane];
        float dx = dirx[e], dy = diry[e], dz = dirz[e];
        float d0 = blo(pds), d1 = bhi(pds);
        float m0 = blo(pvm), m1 = bhi(pvm);
        a0 += d0; a1 += d1;
        vx0 = fmaf(dx, m0, vx0); vx1 = fmaf(dx, m1, vx1);
        vy0 = fmaf(dy, m0, vy0); vy1 = fmaf(dy, m1, vy1);
        vz0 = fmaf(dz, m0, vz0); vz1 = fmaf(dz, m1, vz1);
    }

    float2 sv = ((const float2*)&s[(size_t)n * FDIM])[lane];
    float2 o0 = { sv.x + a0, sv.y + a1 };
    ((float2*)&out[(size_t)n * FDIM])[lane] = o0;

    const float* vb = &v[(size_t)n * 3 * FDIM];
    float* ovb = &out[(size_t)N * FDIM + (size_t)n * 3 * FDIM];
    float2 vv;
    vv = ((const float2*)vb)[lane];
    ((float2*)ovb)[lane] = { vv.x + vx0, vv.y + vx1 };
    vv = ((const float2*)(vb + FDIM))[lane];
    ((float2*)(ovb + FDIM))[lane] = { vv.x + vy0, vv.y + vy1 };
    vv = ((const float2*)(vb + 2 * FDIM))[lane];
    ((float2*)(ovb + 2 * FDIM))[lane] = { vv.x + vz0, vv.y + vz1 };
}

// ---------------- host ----------------

static inline size_t align256(size_t x) { return (x + 255) & ~(size_t)255; }

extern "C" void kernel_launch(void* const* d_in, const int* in_sizes, int n_in,
                              void* d_out, int out_size, void* d_ws, size_t ws_size,
                              hipStream_t stream) {
    const float* s   = (const float*)d_in[0];
    const float* v   = (const float*)d_in[1];
    const float* pos = (const float*)d_in[2];
    const int*   ei  = (const int*)d_in[3];
    const float* W1  = (const float*)d_in[4];
    const float* b1  = (const float*)d_in[5];
    const float* W2  = (const float*)d_in[6];
    const float* b2  = (const float*)d_in[7];
    const float* Wsm = (const float*)d_in[8];
    const float* bsm = (const float*)d_in[9];
    const float* Wvm = (const float*)d_in[10];
    const float* bvm = (const float*)d_in[11];
    const float* centers = (const float*)d_in[12];
    const float* widths  = (const float*)d_in[13];
    float* out = (float*)d_out;

    int N = in_sizes[0] / FDIM;
    int E = in_sizes[3] / 2;
    int nblocks = (E + TE - 1) / TE;

    // workspace layout
    size_t off = 0;
    int* flag = (int*)((char*)d_ws + off);           off = align256(off + 4);
    __bf16* W1t = (__bf16*)((char*)d_ws + off);      off = align256(off + (size_t)256 * K1PAD * 2);
    __bf16* W2t = (__bf16*)((char*)d_ws + off);      off = align256(off + (size_t)256 * TWOF * 2);
    __bf16* W3t = (__bf16*)((char*)d_ws + off);      off = align256(off + (size_t)256 * TWOF * 2);
    int* hist   = (int*)((char*)d_ws + off);         off = align256(off + (size_t)N * 4);
    int* loc    = (int*)((char*)d_ws + off);         off = align256(off + (size_t)N * 4);
    int* bsum   = (int*)((char*)d_ws + off);         off = align256(off + 1024);
    int* rs     = (int*)((char*)d_ws + off);         off = align256(off + (size_t)(N + 1) * 4);
    int* cursor = (int*)((char*)d_ws + off);         off = align256(off + (size_t)N * 4);
    int* elist  = (int*)((char*)d_ws + off);         off = align256(off + (size_t)E * 4);
    float* dirx = (float*)((char*)d_ws + off);       off = align256(off + (size_t)E * 4);
    float* diry = (float*)((char*)d_ws + off);       off = align256(off + (size_t)E * 4);
    float* dirz = (float*)((char*)d_ws + off);       off = align256(off + (size_t)E * 4);
    __bf16* EO  = (__bf16*)((char*)d_ws + off);      off = align256(off + (size_t)nblocks * TE * 256 * 2);
    bool use_csr = (off <= ws_size);

    int nsample = E < 1024 ? E : 1024;
    hipLaunchKernelGGL(sniff_idx, dim3(1), dim3(256), 0, stream, ei, nsample, flag);

    int nprep = 256 * K1PAD + 2 * 256 * TWOF;
    hipLaunchKernelGGL(prep_weights, dim3((nprep + 255) / 256), dim3(256), 0, stream,
                       W1, W2, Wsm, Wvm, W1t, W2t, W3t);

    if (use_csr) {
        int nb = (N + 1023) / 1024;
        hipLaunchKernelGGL(zero_hist, dim3((N + 255) / 256), dim3(256), 0, stream, hist, N);
        hipLaunchKernelGGL(hist_k, dim3((E + 255) / 256), dim3(256), 0, stream, ei, flag, hist, E);
        hipLaunchKernelGGL(scan_a, dim3(nb), dim3(256), 0, stream, hist, loc, bsum, N);
        hipLaunchKernelGGL(scan_b, dim3(1), dim3(64), 0, stream, bsum, nb);
        hipLaunchKernelGGL(scan_c, dim3((N + 255) / 256), dim3(256), 0, stream, loc, bsum, rs, cursor, N, E);
        hipLaunchKernelGGL(scatter_k, dim3((E + 255) / 256), dim3(256), 0, stream, ei, flag, cursor, elist, E);

        hipLaunchKernelGGL(edge_kernel<1>, dim3(nblocks), dim3(256), 0, stream,
                           s, pos, ei, b1, b2, bsm, bvm, centers, widths,
                           W1t, W2t, W3t, flag, EO, dirx, diry, dirz, out, N, E);

        hipLaunchKernelGGL(node_kernel, dim3((N + 3) / 4), dim3(256), 0, stream,
                           s, v, EO, dirx, diry, dirz, rs, elist, out, N);
    } else {
        int nf4    = (N * FDIM) / 4;
        int total4 = N * FDIM;
        hipLaunchKernelGGL(init_out, dim3(8192), dim3(256), 0, stream,
                           (const float4*)s, (const float4*)v, (float4*)out, nf4, total4);
        hipLaunchKernelGGL(edge_kernel<0>, dim3(nblocks), dim3(256), 0, stream,
                           s, pos, ei, b1, b2, bsm, bvm, centers, widths,
                           W1t, W2t, W3t, flag, EO, dirx, diry, dirz, out, N, E);
    }
}

// Round 4
// 776.545 us; speedup vs baseline: 5.6127x; 1.0387x over previous
//
#include <hip/hip_runtime.h>
#include <math.h>

#define FDIM   128
#define TWOF   256
#define NRBF_  20
#define INDIM  276
#define K1PAD  288          // INDIM padded to multiple of 32
#define XS     296          // shared-buffer row stride in bf16 (odd # of 16B chunks)
#define TE     64           // edges per workgroup

typedef __bf16 bf16x8 __attribute__((ext_vector_type(8)));
typedef __bf16 bf16x4 __attribute__((ext_vector_type(4)));
typedef float  f32x4  __attribute__((ext_vector_type(4)));

__device__ inline float blo(unsigned p){ return __uint_as_float(p << 16); }
__device__ inline float bhi(unsigned p){ return __uint_as_float(p & 0xffff0000u); }

// ---------------- helper kernels ----------------

__global__ void sniff_idx(const int* __restrict__ ei, int nsample, int* __restrict__ flag) {
    __shared__ int any;
    if (threadIdx.x == 0) any = 0;
    __syncthreads();
    int nz = 0;
    for (int i = threadIdx.x; i < nsample; i += blockDim.x)
        nz |= (ei[2 * i + 1] != 0);
    if (nz) atomicOr(&any, 1);
    __syncthreads();
    if (threadIdx.x == 0) *flag = any;
}

__global__ void init_out(const float4* __restrict__ s4, const float4* __restrict__ v4,
                         float4* __restrict__ out4, int nf4, int total4) {
    for (int i = blockIdx.x * blockDim.x + threadIdx.x; i < total4;
         i += gridDim.x * blockDim.x)
        out4[i] = (i < nf4) ? s4[i] : v4[i - nf4];
}

__global__ void prep_weights(const float* __restrict__ W1, const float* __restrict__ W2,
                             const float* __restrict__ Ws, const float* __restrict__ Wv,
                             __bf16* __restrict__ W1t, __bf16* __restrict__ W2t,
                             __bf16* __restrict__ W3t) {
    int id = blockIdx.x * 256 + threadIdx.x;
    const int n1 = 256 * K1PAD;
    if (id < n1) {
        int n = id / K1PAD, k = id - n * K1PAD;
        W1t[id] = (k < INDIM) ? (__bf16)W1[k * TWOF + n] : (__bf16)0.f;
    } else if (id < n1 + 65536) {
        int j = id - n1; int n = j >> 8, k = j & 255;
        W2t[j] = (__bf16)W2[k * TWOF + n];
    } else if (id < n1 + 131072) {
        int j = id - n1 - 65536; int n = j >> 8, k = j & 255;
        W3t[j] = (n < FDIM) ? (__bf16)Ws[k * FDIM + n]
                            : (__bf16)Wv[k * FDIM + (n - FDIM)];
    }
}

// ---------------- CSR build ----------------

__global__ void zero_hist(int* __restrict__ hist, int N) {
    int i = blockIdx.x * 256 + threadIdx.x;
    if (i < N) hist[i] = 0;
}

__global__ void hist_k(const int* __restrict__ ei, const int* __restrict__ flag,
                       int* __restrict__ hist, int E) {
    int e = blockIdx.x * 256 + threadIdx.x;
    if (e >= E) return;
    int dst = (*flag == 0) ? ei[2 * (E + e)] : ei[E + e];
    atomicAdd(&hist[dst], 1);
}

__global__ void scan_a(const int* __restrict__ hist, int* __restrict__ loc,
                       int* __restrict__ bsum, int N) {
    __shared__ int sums[256];
    int t = threadIdx.x;
    int base = blockIdx.x * 1024 + t * 4;
    int v0 = (base + 0 < N) ? hist[base + 0] : 0;
    int v1 = (base + 1 < N) ? hist[base + 1] : 0;
    int v2 = (base + 2 < N) ? hist[base + 2] : 0;
    int v3 = (base + 3 < N) ? hist[base + 3] : 0;
    int s = v0 + v1 + v2 + v3;
    sums[t] = s;
    __syncthreads();
    for (int off = 1; off < 256; off <<= 1) {
        int x = (t >= off) ? sums[t - off] : 0;
        __syncthreads();
        sums[t] += x;
        __syncthreads();
    }
    int excl = sums[t] - s;
    if (t == 255) bsum[blockIdx.x] = sums[255];
    if (base + 0 < N) loc[base + 0] = excl; excl += v0;
    if (base + 1 < N) loc[base + 1] = excl; excl += v1;
    if (base + 2 < N) loc[base + 2] = excl; excl += v2;
    if (base + 3 < N) loc[base + 3] = excl;
}

__global__ void scan_b(int* __restrict__ bsum, int nb) {
    if (threadIdx.x == 0 && blockIdx.x == 0) {
        int run = 0;
        for (int i = 0; i < nb; ++i) { int v = bsum[i]; bsum[i] = run; run += v; }
    }
}

__global__ void scan_c(const int* __restrict__ loc, const int* __restrict__ bsum,
                       int* __restrict__ rs, int* __restrict__ cursor, int N, int E) {
    int i = blockIdx.x * 256 + threadIdx.x;
    if (i < N) {
        int v = loc[i] + bsum[i >> 10];
        rs[i] = v; cursor[i] = v;
    }
    if (i == 0) rs[N] = E;
}

// store edge -> CSR slot (perm), not slot -> edge
__global__ void scatter_k(const int* __restrict__ ei, const int* __restrict__ flag,
                          int* __restrict__ cursor, int* __restrict__ perm, int E) {
    int e = blockIdx.x * 256 + threadIdx.x;
    if (e >= E) return;
    int dst = (*flag == 0) ? ei[2 * (E + e)] : ei[E + e];
    int pos = atomicAdd(&cursor[dst], 1);
    perm[e] = pos;
}

// ---------------- main edge kernel ----------------
// Single LDS buffer Sb holds X (L1 input), then H (L1/L2 output), then EO staging.

template<int CSR>
__launch_bounds__(256, 4)
__global__ void edge_kernel(const float* __restrict__ s,
                            const float* __restrict__ pos,
                            const int* __restrict__ ei,
                            const float* __restrict__ b1, const float* __restrict__ b2,
                            const float* __restrict__ bsm, const float* __restrict__ bvm,
                            const float* __restrict__ centers, const float* __restrict__ widths,
                            const __bf16* __restrict__ W1t, const __bf16* __restrict__ W2t,
                            const __bf16* __restrict__ W3t,
                            const int* __restrict__ flag,
                            const int* __restrict__ perm,
                            __bf16* __restrict__ EO,
                            float* __restrict__ dirx, float* __restrict__ diry,
                            float* __restrict__ dirz,
                            float* __restrict__ out, int N, int E) {
    __shared__ __align__(16) __bf16 Sb[TE][XS];
    __shared__ float sdir[3][TE];
    __shared__ int ssrc[TE], sdst[TE], svalid[TE], sperm[TE];

    const int t    = threadIdx.x;
    const int lane = t & 63;
    const int wave = t >> 6;
    const int e0   = blockIdx.x * TE;
    const int i64  = (*flag == 0);

    // ---- Phase A: per-edge prep
    if (t < TE) {
        int e = e0 + t;
        int valid = (e < E);
        int srcn = 0, dstn = 0;
        if (valid) {
            if (i64) { srcn = ei[2 * e]; dstn = ei[2 * (E + e)]; }
            else     { srcn = ei[e];     dstn = ei[E + e]; }
        }
        ssrc[t] = srcn; sdst[t] = dstn; svalid[t] = valid;
        float rx = pos[dstn * 3 + 0] - pos[srcn * 3 + 0];
        float ry = pos[dstn * 3 + 1] - pos[srcn * 3 + 1];
        float rz = pos[dstn * 3 + 2] - pos[srcn * 3 + 2];
        float dist = sqrtf(rx * rx + ry * ry + rz * rz);
        float inv = dist > 0.f ? 1.f / dist : 0.f;
        float dx = rx * inv, dy = ry * inv, dz = rz * inv;
        sdir[0][t] = dx; sdir[1][t] = dy; sdir[2][t] = dz;
        int p = 0;
        if (CSR && valid) {
            p = perm[e];
            dirx[p] = dx; diry[p] = dy; dirz[p] = dz;
        }
        sperm[t] = p;
#pragma unroll
        for (int k = 0; k < 32; ++k) {
            float val = 0.f;
            if (k < NRBF_) {
                float u = (dist - centers[k]) / (widths[k] + 1e-8f);
                val = __expf(-u * u);
            }
            Sb[t][TWOF + k] = (__bf16)val;
        }
    }
    __syncthreads();

    // ---- Phase B: gather s[src]/s[dst] -> X cols 0..255
    {
        const int half = lane >> 5;
        const int q    = lane & 31;
        const float4* s4 = (const float4*)s;
#pragma unroll 4
        for (int i = 0; i < 16; ++i) {
            int e = wave * 16 + i;
            int node = half ? sdst[e] : ssrc[e];
            float4 x = s4[node * 32 + q];
            bf16x4 b; b.x = (__bf16)x.x; b.y = (__bf16)x.y; b.z = (__bf16)x.z; b.w = (__bf16)x.w;
            *(bf16x4*)&Sb[e][half * FDIM + q * 4] = b;
        }
    }
    __syncthreads();

    const int l15 = lane & 15;
    const int kg  = (lane >> 4) * 8;
    const int nbase = wave * 64;

    f32x4 acc[4][4];

    // ================= Layer 1: K=288 (reads X) =================
#pragma unroll
    for (int et = 0; et < 4; ++et)
#pragma unroll
        for (int nt = 0; nt < 4; ++nt) acc[et][nt] = (f32x4)0.f;
    {
        const __bf16* bp[4];
#pragma unroll
        for (int nt = 0; nt < 4; ++nt)
            bp[nt] = &W1t[(size_t)(nbase + nt * 16 + l15) * K1PAD + kg];
        bf16x8 bcur[4];
#pragma unroll
        for (int nt = 0; nt < 4; ++nt) bcur[nt] = *(const bf16x8*)bp[nt];
#pragma unroll
        for (int kc = 0; kc < K1PAD; kc += 32) {
            bf16x8 bnxt[4];
            if (kc + 32 < K1PAD) {
#pragma unroll
                for (int nt = 0; nt < 4; ++nt)
                    bnxt[nt] = *(const bf16x8*)(bp[nt] + kc + 32);
            }
            bf16x8 a[4];
#pragma unroll
            for (int et = 0; et < 4; ++et)
                a[et] = *(const bf16x8*)&Sb[et * 16 + l15][kc + kg];
#pragma unroll
            for (int nt = 0; nt < 4; ++nt)
#pragma unroll
                for (int et = 0; et < 4; ++et)
                    acc[et][nt] = __builtin_amdgcn_mfma_f32_16x16x32_bf16(a[et], bcur[nt], acc[et][nt], 0, 0, 0);
#pragma unroll
            for (int nt = 0; nt < 4; ++nt) bcur[nt] = bnxt[nt];
        }
    }
    __syncthreads();   // all X reads complete before H overwrites the buffer
#pragma unroll
    for (int nt = 0; nt < 4; ++nt) {
        int n = nbase + nt * 16 + l15;
        float bb = b1[n];
#pragma unroll
        for (int et = 0; et < 4; ++et)
#pragma unroll
            for (int r = 0; r < 4; ++r) {
                int m = et * 16 + (lane >> 4) * 4 + r;
                float h = acc[et][nt][r] + bb;
                Sb[m][n] = (__bf16)(h * __builtin_amdgcn_rcpf(1.f + __expf(-h)));
            }
    }
    __syncthreads();

    // ================= Layer 2: K=256 (reads H, rewrites H) =================
#pragma unroll
    for (int et = 0; et < 4; ++et)
#pragma unroll
        for (int nt = 0; nt < 4; ++nt) acc[et][nt] = (f32x4)0.f;
    {
        const __bf16* bp[4];
#pragma unroll
        for (int nt = 0; nt < 4; ++nt)
            bp[nt] = &W2t[(size_t)(nbase + nt * 16 + l15) * TWOF + kg];
        bf16x8 bcur[4];
#pragma unroll
        for (int nt = 0; nt < 4; ++nt) bcur[nt] = *(const bf16x8*)bp[nt];
#pragma unroll
        for (int kc = 0; kc < TWOF; kc += 32) {
            bf16x8 bnxt[4];
            if (kc + 32 < TWOF) {
#pragma unroll
                for (int nt = 0; nt < 4; ++nt)
                    bnxt[nt] = *(const bf16x8*)(bp[nt] + kc + 32);
            }
            bf16x8 a[4];
#pragma unroll
            for (int et = 0; et < 4; ++et)
                a[et] = *(const bf16x8*)&Sb[et * 16 + l15][kc + kg];
#pragma unroll
            for (int nt = 0; nt < 4; ++nt)
#pragma unroll
                for (int et = 0; et < 4; ++et)
                    acc[et][nt] = __builtin_amdgcn_mfma_f32_16x16x32_bf16(a[et], bcur[nt], acc[et][nt], 0, 0, 0);
#pragma unroll
            for (int nt = 0; nt < 4; ++nt) bcur[nt] = bnxt[nt];
        }
    }
    __syncthreads();   // all h1 reads complete before overwrite
#pragma unroll
    for (int nt = 0; nt < 4; ++nt) {
        int n = nbase + nt * 16 + l15;
        float bb = b2[n];
#pragma unroll
        for (int et = 0; et < 4; ++et)
#pragma unroll
            for (int r = 0; r < 4; ++r) {
                int m = et * 16 + (lane >> 4) * 4 + r;
                float h = acc[et][nt][r] + bb;
                Sb[m][n] = (__bf16)(h * __builtin_amdgcn_rcpf(1.f + __expf(-h)));
            }
    }
    __syncthreads();

    // ================= Layer 3: K=256 (reads H) =================
#pragma unroll
    for (int et = 0; et < 4; ++et)
#pragma unroll
        for (int nt = 0; nt < 4; ++nt) acc[et][nt] = (f32x4)0.f;
    {
        const __bf16* bp[4];
#pragma unroll
        for (int nt = 0; nt < 4; ++nt) {
            int rowbase = ((nt >= 2) ? FDIM : 0) + wave * 32 + (nt & 1) * 16 + l15;
            bp[nt] = &W3t[(size_t)rowbase * TWOF + kg];
        }
        bf16x8 bcur[4];
#pragma unroll
        for (int nt = 0; nt < 4; ++nt) bcur[nt] = *(const bf16x8*)bp[nt];
#pragma unroll
        for (int kc = 0; kc < TWOF; kc += 32) {
            bf16x8 bnxt[4];
            if (kc + 32 < TWOF) {
#pragma unroll
                for (int nt = 0; nt < 4; ++nt)
                    bnxt[nt] = *(const bf16x8*)(bp[nt] + kc + 32);
            }
            bf16x8 a[4];
#pragma unroll
            for (int et = 0; et < 4; ++et)
                a[et] = *(const bf16x8*)&Sb[et * 16 + l15][kc + kg];
#pragma unroll
            for (int nt = 0; nt < 4; ++nt)
#pragma unroll
                for (int et = 0; et < 4; ++et)
                    acc[et][nt] = __builtin_amdgcn_mfma_f32_16x16x32_bf16(a[et], bcur[nt], acc[et][nt], 0, 0, 0);
#pragma unroll
            for (int nt = 0; nt < 4; ++nt) bcur[nt] = bnxt[nt];
        }
    }

    float b3v[4];
#pragma unroll
    for (int nt = 0; nt < 4; ++nt) {
        int n = wave * 32 + (nt & 1) * 16 + l15;
        b3v[nt] = (nt < 2) ? bsm[n] : bvm[n];
    }

    if (CSR) {
        __syncthreads();   // all H reads complete before EO staging overwrites buffer
        __bf16 (*EOs)[XS] = (__bf16(*)[XS])(&Sb[0][0]);
#pragma unroll
        for (int nt = 0; nt < 4; ++nt) {
            int col = ((nt >= 2) ? FDIM : 0) + wave * 32 + (nt & 1) * 16 + l15;
            float bb = b3v[nt];
#pragma unroll
            for (int et = 0; et < 4; ++et)
#pragma unroll
                for (int r = 0; r < 4; ++r) {
                    int m = et * 16 + (lane >> 4) * 4 + r;
                    EOs[m][col] = (__bf16)(acc[et][nt][r] + bb);
                }
        }
        __syncthreads();
        uint4* dst4 = (uint4*)EO;
#pragma unroll
        for (int j = 0; j < 8; ++j) {
            int flat = j * 256 + t;          // 0..2047
            int row = flat >> 5, col = flat & 31;
            if (!svalid[row]) continue;
            dst4[(size_t)sperm[row] * 32 + col] = *(const uint4*)&EOs[row][col * 8];
        }
    } else {
        float* outs = out;
        float* outv = out + (size_t)N * FDIM;
#pragma unroll
        for (int et = 0; et < 4; ++et) {
#pragma unroll
            for (int r = 0; r < 4; ++r) {
                int m = et * 16 + (lane >> 4) * 4 + r;
                if (!svalid[m]) continue;
                int dst = sdst[m];
                float dx = sdir[0][m], dy = sdir[1][m], dz = sdir[2][m];
#pragma unroll
                for (int nt = 0; nt < 4; ++nt) {
                    int n = wave * 32 + (nt & 1) * 16 + l15;
                    float val = acc[et][nt][r] + b3v[nt];
                    if (nt < 2) {
                        atomicAdd(&outs[dst * FDIM + n], val);
                    } else {
                        int base = dst * 3 * FDIM + n;
                        atomicAdd(&outv[base],            dx * val);
                        atomicAdd(&outv[base + FDIM],     dy * val);
                        atomicAdd(&outv[base + 2 * FDIM], dz * val);
                    }
                }
            }
        }
    }
}

// ---------------- node aggregation: fully streaming (EO/dir pre-sorted) ----------------

__launch_bounds__(256)
__global__ void node_kernel(const float* __restrict__ s, const float* __restrict__ v,
                            const __bf16* __restrict__ EO,
                            const float* __restrict__ dirx, const float* __restrict__ diry,
                            const float* __restrict__ dirz,
                            const int* __restrict__ rs,
                            float* __restrict__ out, int N) {
    int wave = threadIdx.x >> 6, lane = threadIdx.x & 63;
    int n = blockIdx.x * 4 + wave;
    if (n >= N) return;
    int beg = rs[n], end = rs[n + 1];

    float a0 = 0.f, a1 = 0.f;
    float vx0 = 0.f, vx1 = 0.f, vy0 = 0.f, vy1 = 0.f, vz0 = 0.f, vz1 = 0.f;
    const unsigned* EO32 = (const unsigned*)EO;

#pragma unroll 2
    for (int i = beg; i < end; ++i) {
        unsigned pds = EO32[(size_t)i * 128 + lane];
        unsigned pvm = EO32[(size_t)i * 128 + 64 + lane];
        float dx = dirx[i], dy = diry[i], dz = dirz[i];
        float d0 = blo(pds), d1 = bhi(pds);
        float m0 = blo(pvm), m1 = bhi(pvm);
        a0 += d0; a1 += d1;
        vx0 = fmaf(dx, m0, vx0); vx1 = fmaf(dx, m1, vx1);
        vy0 = fmaf(dy, m0, vy0); vy1 = fmaf(dy, m1, vy1);
        vz0 = fmaf(dz, m0, vz0); vz1 = fmaf(dz, m1, vz1);
    }

    float2 sv = ((const float2*)&s[(size_t)n * FDIM])[lane];
    ((float2*)&out[(size_t)n * FDIM])[lane] = { sv.x + a0, sv.y + a1 };

    const float* vb = &v[(size_t)n * 3 * FDIM];
    float* ovb = &out[(size_t)N * FDIM + (size_t)n * 3 * FDIM];
    float2 vv;
    vv = ((const float2*)vb)[lane];
    ((float2*)ovb)[lane] = { vv.x + vx0, vv.y + vx1 };
    vv = ((const float2*)(vb + FDIM))[lane];
    ((float2*)(ovb + FDIM))[lane] = { vv.x + vy0, vv.y + vy1 };
    vv = ((const float2*)(vb + 2 * FDIM))[lane];
    ((float2*)(ovb + 2 * FDIM))[lane] = { vv.x + vz0, vv.y + vz1 };
}

// ---------------- host ----------------

static inline size_t align256(size_t x) { return (x + 255) & ~(size_t)255; }

extern "C" void kernel_launch(void* const* d_in, const int* in_sizes, int n_in,
                              void* d_out, int out_size, void* d_ws, size_t ws_size,
                              hipStream_t stream) {
    const float* s   = (const float*)d_in[0];
    const float* v   = (const float*)d_in[1];
    const float* pos = (const float*)d_in[2];
    const int*   ei  = (const int*)d_in[3];
    const float* W1  = (const float*)d_in[4];
    const float* b1  = (const float*)d_in[5];
    const float* W2  = (const float*)d_in[6];
    const float* b2  = (const float*)d_in[7];
    const float* Wsm = (const float*)d_in[8];
    const float* bsm = (const float*)d_in[9];
    const float* Wvm = (const float*)d_in[10];
    const float* bvm = (const float*)d_in[11];
    const float* centers = (const float*)d_in[12];
    const float* widths  = (const float*)d_in[13];
    float* out = (float*)d_out;

    int N = in_sizes[0] / FDIM;
    int E = in_sizes[3] / 2;
    int nblocks = (E + TE - 1) / TE;

    // workspace layout
    size_t off = 0;
    int* flag = (int*)((char*)d_ws + off);           off = align256(off + 4);
    __bf16* W1t = (__bf16*)((char*)d_ws + off);      off = align256(off + (size_t)256 * K1PAD * 2);
    __bf16* W2t = (__bf16*)((char*)d_ws + off);      off = align256(off + (size_t)256 * TWOF * 2);
    __bf16* W3t = (__bf16*)((char*)d_ws + off);      off = align256(off + (size_t)256 * TWOF * 2);
    int* hist   = (int*)((char*)d_ws + off);         off = align256(off + (size_t)N * 4);
    int* loc    = (int*)((char*)d_ws + off);         off = align256(off + (size_t)N * 4);
    int* bsum   = (int*)((char*)d_ws + off);         off = align256(off + 1024);
    int* rs     = (int*)((char*)d_ws + off);         off = align256(off + (size_t)(N + 1) * 4);
    int* cursor = (int*)((char*)d_ws + off);         off = align256(off + (size_t)N * 4);
    int* perm   = (int*)((char*)d_ws + off);         off = align256(off + (size_t)E * 4);
    float* dirx = (float*)((char*)d_ws + off);       off = align256(off + (size_t)E * 4);
    float* diry = (float*)((char*)d_ws + off);       off = align256(off + (size_t)E * 4);
    float* dirz = (float*)((char*)d_ws + off);       off = align256(off + (size_t)E * 4);
    __bf16* EO  = (__bf16*)((char*)d_ws + off);      off = align256(off + (size_t)E * 256 * 2);
    bool use_csr = (off <= ws_size);

    int nsample = E < 1024 ? E : 1024;
    hipLaunchKernelGGL(sniff_idx, dim3(1), dim3(256), 0, stream, ei, nsample, flag);

    int nprep = 256 * K1PAD + 2 * 256 * TWOF;
    hipLaunchKernelGGL(prep_weights, dim3((nprep + 255) / 256), dim3(256), 0, stream,
                       W1, W2, Wsm, Wvm, W1t, W2t, W3t);

    if (use_csr) {
        int nb = (N + 1023) / 1024;
        hipLaunchKernelGGL(zero_hist, dim3((N + 255) / 256), dim3(256), 0, stream, hist, N);
        hipLaunchKernelGGL(hist_k, dim3((E + 255) / 256), dim3(256), 0, stream, ei, flag, hist, E);
        hipLaunchKernelGGL(scan_a, dim3(nb), dim3(256), 0, stream, hist, loc, bsum, N);
        hipLaunchKernelGGL(scan_b, dim3(1), dim3(64), 0, stream, bsum, nb);
        hipLaunchKernelGGL(scan_c, dim3((N + 255) / 256), dim3(256), 0, stream, loc, bsum, rs, cursor, N, E);
        hipLaunchKernelGGL(scatter_k, dim3((E + 255) / 256), dim3(256), 0, stream, ei, flag, cursor, perm, E);

        hipLaunchKernelGGL(edge_kernel<1>, dim3(nblocks), dim3(256), 0, stream,
                           s, pos, ei, b1, b2, bsm, bvm, centers, widths,
                           W1t, W2t, W3t, flag, perm, EO, dirx, diry, dirz, out, N, E);

        hipLaunchKernelGGL(node_kernel, dim3((N + 3) / 4), dim3(256), 0, stream,
                           s, v, EO, dirx, diry, dirz, rs, out, N);
    } else {
        int nf4    = (N * FDIM) / 4;
        int total4 = N * FDIM;
        hipLaunchKernelGGL(init_out, dim3(8192), dim3(256), 0, stream,
                           (const float4*)s, (const float4*)v, (float4*)out, nf4, total4);
        hipLaunchKernelGGL(edge_kernel<0>, dim3(nblocks), dim3(256), 0, stream,
                           s, pos, ei, b1, b2, bsm, bvm, centers, widths,
                           W1t, W2t, W3t, flag, perm, EO, dirx, diry, dirz, out, N, E);
    }
}